// Round 5
// baseline (159.197 us; speedup 1.0000x reference)
//
#include <hip/hip_runtime.h>
#include <hip/hip_bf16.h>

#define L_SEQ    1024
#define IN_DIM   256
#define DIM_MSA  32
#define PAIR_DIM 64
#define ISPLIT   16
#define ICHUNK   (L_SEQ / ISPLIT)   // 64

typedef float f2v __attribute__((ext_vector_type(2)));

// s[i][c] = b1[c] + sum_d seq[i][d] * W1[c][d]
__global__ void k_proj1(const float* __restrict__ seq, const float* __restrict__ W1,
                        const float* __restrict__ b1, float* __restrict__ s) {
    int t = blockIdx.x * blockDim.x + threadIdx.x;   // 1024*32 threads
    int i = t >> 5, c = t & 31;
    const float4* sq = (const float4*)(seq + i * IN_DIM);
    const float4* w  = (const float4*)(W1  + c * IN_DIM);
    float a0 = 0.f, a1 = 0.f, a2 = 0.f, a3 = 0.f;
#pragma unroll
    for (int d4 = 0; d4 < IN_DIM / 4; ++d4) {
        float4 x = sq[d4], y = w[d4];
        a0 += x.x * y.x;  a1 += x.y * y.y;
        a2 += x.z * y.z;  a3 += x.w * y.w;
    }
    s[t] = b1[c] + ((a0 + a1) + (a2 + a3));
}

// tmp[j][p][d] = sum_c s[j][c] * W2[p][c*32+d]   (thread computes 4 consecutive d)
__global__ void k_proj2(const float* __restrict__ s, const float* __restrict__ W2,
                        float* __restrict__ tmp) {
    int t = blockIdx.x * blockDim.x + threadIdx.x;   // 1024*64*8 threads
    int q = t & 7, p = (t >> 3) & 63, j = t >> 9;
    const float4* w  = (const float4*)W2;            // idx = p*256 + c*8 + q
    const float*  sj = s + j * DIM_MSA;
    float4 acc = {0.f, 0.f, 0.f, 0.f};
#pragma unroll
    for (int c = 0; c < DIM_MSA; ++c) {
        float  sc = sj[c];
        float4 wv = w[p * 256 + c * 8 + q];
        acc.x += sc * wv.x;  acc.y += sc * wv.y;
        acc.z += sc * wv.z;  acc.w += sc * wv.w;
    }
    ((float4*)tmp)[t] = acc;   // t = j*512 + p*8 + q  ==  [j][p][d] as float4
}

// out[i][j][p] = sum_d s[i][d]*tmp[j][p][d] + b2[p] + pair[i][j][p]
// One wave per (j-pair, i-chunk). lane l -> (jj = l>>5, p = 2*(l&31), 2 p's).
// Wave's 64 float2 lanes cover the contiguous 128 floats pair[i][j0..j0+1][:].
// tmp fragments for the lane's two p-rows live in 16 NAMED float4s (64 VGPRs).
__global__ __launch_bounds__(256, 4) void k_outer(
    const float* __restrict__ s, const float* __restrict__ tmp,
    const float* __restrict__ pair, const float* __restrict__ b2,
    float* __restrict__ out) {
    __shared__ float s_lds[ICHUNK * DIM_MSA];   // 8 KB

    int tid  = threadIdx.x;
    int wave = tid >> 6, lane = tid & 63;
    int jgrp  = blockIdx.x & 127;               // 128 j-groups of 8 j
    int chunk = blockIdx.x >> 7;                // ISPLIT i-chunks
    int j0 = jgrp * 8 + wave * 2;               // this wave: j0, j0+1
    int i0 = chunk * ICHUNK;
    int jj = lane >> 5;                         // which of the two j's
    int pp = (lane & 31) * 2;                   // p, p+1

    // stage s[i0 .. i0+ICHUNK) -> LDS (2048 floats, 512 float4, 2 per thread)
    const float4* s4g = (const float4*)(s + i0 * DIM_MSA);
    float4* l4 = (float4*)s_lds;
    l4[tid]       = s4g[tid];
    l4[tid + 256] = s4g[tid + 256];

    // tmp rows [j0+jj][pp][:] and [j0+jj][pp+1][:] -> 16 named float4s
    const float4* t0 = (const float4*)(tmp + (size_t)((j0 + jj) * PAIR_DIM + pp) * DIM_MSA);
    float4 r00 = t0[0], r01 = t0[1], r02 = t0[2], r03 = t0[3],
           r04 = t0[4], r05 = t0[5], r06 = t0[6], r07 = t0[7];
    float4 r10 = t0[8], r11 = t0[9], r12 = t0[10], r13 = t0[11],
           r14 = t0[12], r15 = t0[13], r16 = t0[14], r17 = t0[15];
    float bias0 = b2[pp], bias1 = b2[pp + 1];
    __syncthreads();

    const size_t stride2 = (size_t)L_SEQ * PAIR_DIM / 2;         // in float2 units
    const f2v* pr = (const f2v*)(pair + ((size_t)i0 * L_SEQ + j0) * PAIR_DIM) + lane;
    f2v*       po = (f2v*)(out + ((size_t)i0 * L_SEQ + j0) * PAIR_DIM) + lane;

    f2v A = pr[0];                                               // i0
    f2v Bv = pr[stride2];                                        // i0+1
    pr += 2 * stride2;                                           // points at i0+2

#pragma unroll 2
    for (int it = 0; it < ICHUNK - 2; ++it) {
        f2v Cv = *pr;  pr += stride2;                            // prefetch it+2
        const float4* sv = (const float4*)(s_lds + it * DIM_MSA);
        float4 s0 = sv[0], s1 = sv[1], s2 = sv[2], s3 = sv[3];
        float a0 = s0.x*r00.x + s0.y*r00.y + s0.z*r00.z + s0.w*r00.w
                 + s1.x*r01.x + s1.y*r01.y + s1.z*r01.z + s1.w*r01.w;
        float a1 = s2.x*r02.x + s2.y*r02.y + s2.z*r02.z + s2.w*r02.w
                 + s3.x*r03.x + s3.y*r03.y + s3.z*r03.z + s3.w*r03.w;
        float c0 = s0.x*r10.x + s0.y*r10.y + s0.z*r10.z + s0.w*r10.w
                 + s1.x*r11.x + s1.y*r11.y + s1.z*r11.z + s1.w*r11.w;
        float c1 = s2.x*r12.x + s2.y*r12.y + s2.z*r12.z + s2.w*r12.w
                 + s3.x*r13.x + s3.y*r13.y + s3.z*r13.z + s3.w*r13.w;
        float4 s4 = sv[4], s5 = sv[5], s6 = sv[6], s7 = sv[7];
        float a2 = s4.x*r04.x + s4.y*r04.y + s4.z*r04.z + s4.w*r04.w
                 + s5.x*r05.x + s5.y*r05.y + s5.z*r05.z + s5.w*r05.w;
        float a3 = s6.x*r06.x + s6.y*r06.y + s6.z*r06.z + s6.w*r06.w
                 + s7.x*r07.x + s7.y*r07.y + s7.z*r07.z + s7.w*r07.w;
        float c2 = s4.x*r14.x + s4.y*r14.y + s4.z*r14.z + s4.w*r14.w
                 + s5.x*r15.x + s5.y*r15.y + s5.z*r15.z + s5.w*r15.w;
        float c3 = s6.x*r16.x + s6.y*r16.y + s6.z*r16.z + s6.w*r16.w
                 + s7.x*r17.x + s7.y*r17.y + s7.z*r17.z + s7.w*r17.w;
        f2v o;
        o.x = ((a0 + a1) + (a2 + a3)) + bias0 + A.x;
        o.y = ((c0 + c1) + (c2 + c3)) + bias1 + A.y;
        __builtin_nontemporal_store(o, po);
        po += stride2;
        A = Bv;  Bv = Cv;
    }
#pragma unroll
    for (int t2 = 0; t2 < 2; ++t2) {                             // peeled last two
        int it = ICHUNK - 2 + t2;
        const float4* sv = (const float4*)(s_lds + it * DIM_MSA);
        float4 s0 = sv[0], s1 = sv[1], s2 = sv[2], s3 = sv[3],
               s4 = sv[4], s5 = sv[5], s6 = sv[6], s7 = sv[7];
        float a0 = s0.x*r00.x + s0.y*r00.y + s0.z*r00.z + s0.w*r00.w
                 + s1.x*r01.x + s1.y*r01.y + s1.z*r01.z + s1.w*r01.w;
        float a1 = s2.x*r02.x + s2.y*r02.y + s2.z*r02.z + s2.w*r02.w
                 + s3.x*r03.x + s3.y*r03.y + s3.z*r03.z + s3.w*r03.w;
        float a2 = s4.x*r04.x + s4.y*r04.y + s4.z*r04.z + s4.w*r04.w
                 + s5.x*r05.x + s5.y*r05.y + s5.z*r05.z + s5.w*r05.w;
        float a3 = s6.x*r06.x + s6.y*r06.y + s6.z*r06.z + s6.w*r06.w
                 + s7.x*r07.x + s7.y*r07.y + s7.z*r07.z + s7.w*r07.w;
        float c0 = s0.x*r10.x + s0.y*r10.y + s0.z*r10.z + s0.w*r10.w
                 + s1.x*r11.x + s1.y*r11.y + s1.z*r11.z + s1.w*r11.w;
        float c1 = s2.x*r12.x + s2.y*r12.y + s2.z*r12.z + s2.w*r12.w
                 + s3.x*r13.x + s3.y*r13.y + s3.z*r13.z + s3.w*r13.w;
        float c2 = s4.x*r14.x + s4.y*r14.y + s4.z*r14.z + s4.w*r14.w
                 + s5.x*r15.x + s5.y*r15.y + s5.z*r15.z + s5.w*r15.w;
        float c3 = s6.x*r16.x + s6.y*r16.y + s6.z*r16.z + s6.w*r16.w
                 + s7.x*r17.x + s7.y*r17.y + s7.z*r17.z + s7.w*r17.w;
        f2v o;
        o.x = ((a0 + a1) + (a2 + a3)) + bias0 + A.x;
        o.y = ((c0 + c1) + (c2 + c3)) + bias1 + A.y;
        __builtin_nontemporal_store(o, po);
        po += stride2;
        A = Bv;
    }
}

extern "C" void kernel_launch(void* const* d_in, const int* in_sizes, int n_in,
                              void* d_out, int out_size, void* d_ws, size_t ws_size,
                              hipStream_t stream) {
    const float* seq  = (const float*)d_in[0];   // [1,1024,256]
    const float* pair = (const float*)d_in[1];   // [1,1024,1024,64]
    const float* W1   = (const float*)d_in[2];   // [32,256]
    const float* b1   = (const float*)d_in[3];   // [32]
    const float* W2   = (const float*)d_in[4];   // [64,1024]
    const float* b2   = (const float*)d_in[5];   // [64]
    float* out = (float*)d_out;

    float* s_ws   = (float*)d_ws;                         // 1024*32   = 128 KB
    float* tmp_ws = s_ws + (size_t)L_SEQ * DIM_MSA;       // 1024*64*32 = 8 MB

    k_proj1<<<(L_SEQ * DIM_MSA) / 256, 256, 0, stream>>>(seq, W1, b1, s_ws);
    k_proj2<<<(L_SEQ * PAIR_DIM * (DIM_MSA / 4)) / 256, 256, 0, stream>>>(s_ws, W2, tmp_ws);
    k_outer<<<128 * ISPLIT, 256, 0, stream>>>(s_ws, tmp_ws, pair, b2, out);
}

// Round 6
// 150.179 us; speedup vs baseline: 1.0601x; 1.0601x over previous
//
#include <hip/hip_runtime.h>
#include <hip/hip_bf16.h>

#define L_SEQ    1024
#define IN_DIM   256
#define DIM_MSA  32
#define PAIR_DIM 64
#define ISPLIT   16
#define ICHUNK   (L_SEQ / ISPLIT)   // 64

typedef float f2v __attribute__((ext_vector_type(2)));
typedef float f4v __attribute__((ext_vector_type(4)));

// s[i][c] = b1[c] + sum_d seq[i][d] * W1[c][d]
__global__ void k_proj1(const float* __restrict__ seq, const float* __restrict__ W1,
                        const float* __restrict__ b1, float* __restrict__ s) {
    int t = blockIdx.x * blockDim.x + threadIdx.x;   // 1024*32 threads
    int i = t >> 5, c = t & 31;
    const float4* sq = (const float4*)(seq + i * IN_DIM);
    const float4* w  = (const float4*)(W1  + c * IN_DIM);
    float a0 = 0.f, a1 = 0.f, a2 = 0.f, a3 = 0.f;
#pragma unroll
    for (int d4 = 0; d4 < IN_DIM / 4; ++d4) {
        float4 x = sq[d4], y = w[d4];
        a0 += x.x * y.x;  a1 += x.y * y.y;
        a2 += x.z * y.z;  a3 += x.w * y.w;
    }
    s[t] = b1[c] + ((a0 + a1) + (a2 + a3));
}

// tmp[j][p][d] = sum_c s[j][c] * W2[p][c*32+d]   (thread computes 4 consecutive d)
__global__ void k_proj2(const float* __restrict__ s, const float* __restrict__ W2,
                        float* __restrict__ tmp) {
    int t = blockIdx.x * blockDim.x + threadIdx.x;   // 1024*64*8 threads
    int q = t & 7, p = (t >> 3) & 63, j = t >> 9;
    const float4* w  = (const float4*)W2;            // idx = p*256 + c*8 + q
    const float*  sj = s + j * DIM_MSA;
    float4 acc = {0.f, 0.f, 0.f, 0.f};
#pragma unroll
    for (int c = 0; c < DIM_MSA; ++c) {
        float  sc = sj[c];
        float4 wv = w[p * 256 + c * 8 + q];
        acc.x += sc * wv.x;  acc.y += sc * wv.y;
        acc.z += sc * wv.z;  acc.w += sc * wv.w;
    }
    ((float4*)tmp)[t] = acc;   // t = j*512 + p*8 + q  ==  [j][p][d] as float4
}

// out[i][j][p] = sum_d s[i][d]*tmp[j][p][d] + b2[p] + pair[i][j][p]
// One wave per (j-pair, i-chunk). lane l -> (jj = l>>5, p = 2*(l&31)).
// tmp fragments: 16 named f4v, pinned in VGPRs. s[i,:] is WAVE-UNIFORM ->
// scalar loads (SGPRs, K$); v_fmac vdst, s, v needs no LDS at all.
__global__ __launch_bounds__(256)
__attribute__((amdgpu_waves_per_eu(4, 4)))
void k_outer(
    const float* __restrict__ s, const float* __restrict__ tmp,
    const float* __restrict__ pair, const float* __restrict__ b2,
    float* __restrict__ out) {
    int tid  = threadIdx.x;
    int wave = tid >> 6, lane = tid & 63;
    int jgrp  = blockIdx.x & 127;               // 128 j-groups of 8 j
    int chunk = blockIdx.x >> 7;                // ISPLIT i-chunks
    int j0 = jgrp * 8 + wave * 2;               // this wave: j0, j0+1
    int i0 = chunk * ICHUNK;
    int jj = lane >> 5;                         // which of the two j's
    int pp = (lane & 31) * 2;                   // p, p+1

    // tmp rows [j0+jj][pp][:] and [j0+jj][pp+1][:] -> 16 named f4v (64 VGPRs)
    const f4v* t0 = (const f4v*)(tmp + (size_t)((j0 + jj) * PAIR_DIM + pp) * DIM_MSA);
    f4v r00 = t0[0],  r01 = t0[1],  r02 = t0[2],  r03 = t0[3],
        r04 = t0[4],  r05 = t0[5],  r06 = t0[6],  r07 = t0[7];
    f4v r10 = t0[8],  r11 = t0[9],  r12 = t0[10], r13 = t0[11],
        r14 = t0[12], r15 = t0[13], r16 = t0[14], r17 = t0[15];
    // pin fragments in VGPRs — forbid the scheduler from re-sinking the loads
    asm volatile("" : "+v"(r00), "+v"(r01), "+v"(r02), "+v"(r03),
                      "+v"(r04), "+v"(r05), "+v"(r06), "+v"(r07));
    asm volatile("" : "+v"(r10), "+v"(r11), "+v"(r12), "+v"(r13),
                      "+v"(r14), "+v"(r15), "+v"(r16), "+v"(r17));
    float bias0 = b2[pp], bias1 = b2[pp + 1];

    const size_t stride2 = (size_t)L_SEQ * PAIR_DIM / 2;         // in f2v units
    const f2v* pr = (const f2v*)(pair + ((size_t)i0 * L_SEQ + j0) * PAIR_DIM) + lane;
    f2v*       po = (f2v*)(out + ((size_t)i0 * L_SEQ + j0) * PAIR_DIM) + lane;

    f2v A = pr[0];                                               // i0
    f2v Bv = pr[stride2];                                        // i0+1
    pr += 2 * stride2;                                           // points at i0+2

#pragma unroll 2
    for (int it = 0; it < ICHUNK; ++it) {
        f2v Cv;
        if (it < ICHUNK - 2) { Cv = *pr; pr += stride2; }        // prefetch it+2
        // s[i0+it][0..31] — uniform address -> scalar loads (SGPRs)
        const f4v* sg = (const f4v*)(s + (size_t)(i0 + it) * DIM_MSA);
        f4v s0 = sg[0], s1 = sg[1], s2 = sg[2], s3 = sg[3],
            s4 = sg[4], s5 = sg[5], s6 = sg[6], s7 = sg[7];
        float a0 = s0.x*r00.x + s0.y*r00.y + s0.z*r00.z + s0.w*r00.w
                 + s1.x*r01.x + s1.y*r01.y + s1.z*r01.z + s1.w*r01.w;
        float a1 = s2.x*r02.x + s2.y*r02.y + s2.z*r02.z + s2.w*r02.w
                 + s3.x*r03.x + s3.y*r03.y + s3.z*r03.z + s3.w*r03.w;
        float c0 = s0.x*r10.x + s0.y*r10.y + s0.z*r10.z + s0.w*r10.w
                 + s1.x*r11.x + s1.y*r11.y + s1.z*r11.z + s1.w*r11.w;
        float c1 = s2.x*r12.x + s2.y*r12.y + s2.z*r12.z + s2.w*r12.w
                 + s3.x*r13.x + s3.y*r13.y + s3.z*r13.z + s3.w*r13.w;
        float a2 = s4.x*r04.x + s4.y*r04.y + s4.z*r04.z + s4.w*r04.w
                 + s5.x*r05.x + s5.y*r05.y + s5.z*r05.z + s5.w*r05.w;
        float a3 = s6.x*r06.x + s6.y*r06.y + s6.z*r06.z + s6.w*r06.w
                 + s7.x*r07.x + s7.y*r07.y + s7.z*r07.z + s7.w*r07.w;
        float c2 = s4.x*r14.x + s4.y*r14.y + s4.z*r14.z + s4.w*r14.w
                 + s5.x*r15.x + s5.y*r15.y + s5.z*r15.z + s5.w*r15.w;
        float c3 = s6.x*r16.x + s6.y*r16.y + s6.z*r16.z + s6.w*r16.w
                 + s7.x*r17.x + s7.y*r17.y + s7.z*r17.z + s7.w*r17.w;
        f2v o;
        o.x = ((a0 + a1) + (a2 + a3)) + bias0 + A.x;
        o.y = ((c0 + c1) + (c2 + c3)) + bias1 + A.y;
        __builtin_nontemporal_store(o, po);
        po += stride2;
        A = Bv;  Bv = Cv;
    }
}

extern "C" void kernel_launch(void* const* d_in, const int* in_sizes, int n_in,
                              void* d_out, int out_size, void* d_ws, size_t ws_size,
                              hipStream_t stream) {
    const float* seq  = (const float*)d_in[0];   // [1,1024,256]
    const float* pair = (const float*)d_in[1];   // [1,1024,1024,64]
    const float* W1   = (const float*)d_in[2];   // [32,256]
    const float* b1   = (const float*)d_in[3];   // [32]
    const float* W2   = (const float*)d_in[4];   // [64,1024]
    const float* b2   = (const float*)d_in[5];   // [64]
    float* out = (float*)d_out;

    float* s_ws   = (float*)d_ws;                         // 1024*32   = 128 KB
    float* tmp_ws = s_ws + (size_t)L_SEQ * DIM_MSA;       // 1024*64*32 = 8 MB

    k_proj1<<<(L_SEQ * DIM_MSA) / 256, 256, 0, stream>>>(seq, W1, b1, s_ws);
    k_proj2<<<(L_SEQ * PAIR_DIM * (DIM_MSA / 4)) / 256, 256, 0, stream>>>(s_ws, W2, tmp_ws);
    k_outer<<<128 * ISPLIT, 256, 0, stream>>>(s_ws, tmp_ws, pair, b2, out);
}